// Round 3
// baseline (658.425 us; speedup 1.0000x reference)
//
#include <hip/hip_runtime.h>

#define NROWS 16384
#define DDIM  4096
#define NEXP  64
#define TAU   1e-3f

// ---------------- Kernel A: fp32 partial GEMM ----------------
// 1 wave (64 thr) per block; 64 rows x 64 experts, DK=32 K-tiles.
// grid = 256 * KS; block (rb,kq) accumulates k-range kq*(4096/KS).
// LDS: xs row-major with f4-XOR swizzle (word = row*32 + ((k>>2)^(row>>3))*4 + (k&3))
//      -> a-reads: 8 distinct bank-groups, broadcast, conflict-free.
// Wt linear [k][e] -> b-reads broadcast b128.
__global__ __launch_bounds__(64) void gemm_partial(
    const float* __restrict__ x, const float* __restrict__ Wg,
    float* __restrict__ partials, int ks_shift)
{
    __shared__ float xs[64 * 32];   // 8 KB
    __shared__ float Wt[32 * 64];   // 8 KB

    const int l  = threadIdx.x;
    const int rg = l >> 3;          // 0..7: owns rows rg*8..+7
    const int cg = l & 7;           // 0..7: owns experts cg*8..+7
    const int KS = 1 << ks_shift;
    const int kper = DDIM >> ks_shift;
    const int T  = kper >> 5;       // DK=32 tiles
    const int rb = (int)blockIdx.x >> ks_shift;
    const int kq = (int)blockIdx.x & (KS - 1);

    const int xrl = l >> 3;         // staging: row = i*8 + xrl
    const int xf4 = l & 7;          //          f4col = xf4
    const float* xbase = x + (size_t)(rb * 64) * DDIM + kq * kper;
    const float* wbase = Wg + (size_t)(kq * kper) * NEXP;

    float4 px[8], pw[8];
    #pragma unroll
    for (int i = 0; i < 8; ++i) {   // preload tile 0
        px[i] = *(const float4*)(xbase + (size_t)(i * 8 + xrl) * DDIM + xf4 * 4);
        pw[i] = *(const float4*)(wbase + (size_t)(i * 4 + (l >> 4)) * NEXP + (l & 15) * 4);
    }

    float acc[8][8];
    #pragma unroll
    for (int i = 0; i < 8; ++i)
        #pragma unroll
        for (int j = 0; j < 8; ++j) acc[i][j] = 0.f;

    for (int t = 0; t < T; ++t) {
        __syncthreads();
        #pragma unroll
        for (int i = 0; i < 8; ++i) {            // stage regs -> LDS
            const int row = i * 8 + xrl;         // row>>3 == i
            *(float4*)&xs[row * 32 + ((xf4 ^ i) * 4)] = px[i];
            *(float4*)&Wt[(i * 4 + (l >> 4)) * 64 + (l & 15) * 4] = pw[i];
        }
        __syncthreads();
        if (t + 1 < T) {                         // prefetch next tile
            const float* xp = xbase + (t + 1) * 32;
            const float* wp = wbase + (size_t)((t + 1) * 32) * NEXP;
            #pragma unroll
            for (int i = 0; i < 8; ++i) {
                px[i] = *(const float4*)(xp + (size_t)(i * 8 + xrl) * DDIM + xf4 * 4);
                pw[i] = *(const float4*)(wp + (size_t)(i * 4 + (l >> 4)) * NEXP + (l & 15) * 4);
            }
        }
        #pragma unroll
        for (int k = 0; k < 32; ++k) {
            const int coff = ((k >> 2) ^ rg) * 4 + (k & 3);   // un-swizzle (row>>3==rg)
            float a[8], b[8];
            #pragma unroll
            for (int i = 0; i < 8; ++i) a[i] = xs[(rg * 8 + i) * 32 + coff];
            const float4 b0 = *(const float4*)&Wt[k * 64 + cg * 8];
            const float4 b1 = *(const float4*)&Wt[k * 64 + cg * 8 + 4];
            b[0] = b0.x; b[1] = b0.y; b[2] = b0.z; b[3] = b0.w;
            b[4] = b1.x; b[5] = b1.y; b[6] = b1.z; b[7] = b1.w;
            #pragma unroll
            for (int i = 0; i < 8; ++i)
                #pragma unroll
                for (int j = 0; j < 8; ++j)
                    acc[i][j] = fmaf(a[i], b[j], acc[i][j]);
        }
    }

    float* po = partials + ((size_t)(rb << ks_shift) + kq) * (64 * 64);
    #pragma unroll
    for (int i = 0; i < 8; ++i) {
        *(float4*)(po + (rg * 8 + i) * 64 + cg * 8) =
            make_float4(acc[i][0], acc[i][1], acc[i][2], acc[i][3]);
        *(float4*)(po + (rg * 8 + i) * 64 + cg * 8 + 4) =
            make_float4(acc[i][4], acc[i][5], acc[i][6], acc[i][7]);
    }
}

// ---------------- Kernel B: combine + softmax + top-9 + flags ----------------
__global__ __launch_bounds__(256) void combine_epilogue(
    const float* __restrict__ partials, const float* __restrict__ noise,
    float* __restrict__ out_gates, float* __restrict__ out_idx,
    float* __restrict__ ws_imp, float* __restrict__ ws_load,
    int* __restrict__ flags, int ks_shift)
{
    __shared__ float red[4][NEXP];
    const int tid = threadIdx.x, lane = tid & 63, w = tid >> 6;
    const int rb = blockIdx.x;
    const int KS = 1 << ks_shift;

    float impacc = 0.f, loadacc = 0.f;
    for (int rr = 0; rr < 16; ++rr) {
        const int row = w * 16 + rr;
        const int grow = rb * 64 + row;
        float v = noise[(size_t)grow * NEXP + lane];
        const float* pp = partials + ((size_t)(rb << ks_shift)) * 4096 + row * 64 + lane;
        for (int q = 0; q < KS; ++q) v += pp[(size_t)q * 4096];   // fixed order

        float m = v;
        #pragma unroll
        for (int off = 32; off; off >>= 1) m = fmaxf(m, __shfl_xor(m, off));
        const float ex = __expf(v - m);
        float s = ex;
        #pragma unroll
        for (int off = 32; off; off >>= 1) s += __shfl_xor(s, off);
        const float g = ex * (1.0f / s);
        impacc += g;

        // top-9 keyed on fp32 logit v (monotonic with gates); flag near-ties
        float work = v, vprev = 0.f;
        float myv = 0.f, sumtop = 0.f;
        int myi = 0, mine = 0, flg = 0;
        #pragma unroll
        for (int j = 0; j < 9; ++j) {
            float bv = work, bg = g; int bi = lane;
            #pragma unroll
            for (int off = 32; off; off >>= 1) {
                const float ov = __shfl_xor(bv, off);
                const int   oi = __shfl_xor(bi, off);
                const float og = __shfl_xor(bg, off);
                if (ov > bv || (ov == bv && oi < bi)) { bv = ov; bi = oi; bg = og; }
            }
            if (j > 0) flg |= (vprev - bv < TAU) ? 1 : 0;
            vprev = bv;
            if (j < 8) {
                sumtop += bg;
                if (lane == j)  { myv = bg; myi = bi; }
                if (lane == bi) { work = -3e38f; mine = 1; }
            }
        }
        loadacc += (float)mine;

        if (lane < 8) {
            out_gates[(size_t)grow * 8 + lane] = myv / sumtop;
            out_idx  [(size_t)grow * 8 + lane] = (float)myi;
        }
        if (lane == 0) flags[grow] = flg;
    }

    red[w][lane] = impacc;
    __syncthreads();
    if (w == 0)
        ws_imp[(size_t)rb * NEXP + lane] =
            red[0][lane] + red[1][lane] + red[2][lane] + red[3][lane];
    __syncthreads();
    red[w][lane] = loadacc;
    __syncthreads();
    if (w == 0)
        ws_load[(size_t)rb * NEXP + lane] =
            red[0][lane] + red[1][lane] + red[2][lane] + red[3][lane];
}

// ---------------- Kernel C: fp64 repair of flagged rows ----------------
__global__ __launch_bounds__(256) void repair_rows(
    const float* __restrict__ x, const float* __restrict__ Wg,
    const float* __restrict__ noise, const int* __restrict__ flags,
    float* __restrict__ out_gates, float* __restrict__ out_idx)
{
    __shared__ float xr[DDIM];          // 16 KB
    __shared__ double red64[4][NEXP];   // 2 KB
    const int tid = threadIdx.x, lane = tid & 63, w = tid >> 6;

    for (int r = 0; r < 64; ++r) {
        const int grow = (int)blockIdx.x * 64 + r;
        if (!flags[grow]) continue;     // block-uniform branch
        __syncthreads();                // prior row's LDS fully consumed
        #pragma unroll
        for (int i = 0; i < 4; ++i)
            ((float4*)xr)[tid + 256 * i] =
                ((const float4*)(x + (size_t)grow * DDIM))[tid + 256 * i];
        __syncthreads();

        // wave w covers k-chunk w*1024; lane = expert; 4 chains for latency
        double a0 = 0, a1 = 0, a2 = 0, a3 = 0;
        const float* wp = Wg + (size_t)(w * 1024) * NEXP + lane;
        const float* xp = xr + w * 1024;
        for (int k = 0; k < 1024; k += 4) {
            a0 = fma((double)xp[k + 0], (double)wp[(size_t)(k + 0) * NEXP], a0);
            a1 = fma((double)xp[k + 1], (double)wp[(size_t)(k + 1) * NEXP], a1);
            a2 = fma((double)xp[k + 2], (double)wp[(size_t)(k + 2) * NEXP], a2);
            a3 = fma((double)xp[k + 3], (double)wp[(size_t)(k + 3) * NEXP], a3);
        }
        red64[w][lane] = ((a0 + a1) + a2) + a3;
        __syncthreads();

        if (w == 0) {
            const double v64 = (((red64[0][lane] + red64[1][lane]) + red64[2][lane])
                                + red64[3][lane]) + (double)noise[(size_t)grow * NEXP + lane];
            double m = v64;
            #pragma unroll
            for (int off = 32; off; off >>= 1) m = fmax(m, __shfl_xor(m, off));
            const float ex = __expf((float)(v64 - m));
            float s = ex;
            #pragma unroll
            for (int off = 32; off; off >>= 1) s += __shfl_xor(s, off);
            const float g = ex * (1.0f / s);

            double work = v64;
            float myv = 0.f, sumtop = 0.f, bg;
            int myi = 0;
            #pragma unroll
            for (int j = 0; j < 8; ++j) {
                double bv = work; int bi = lane; bg = g;
                #pragma unroll
                for (int off = 32; off; off >>= 1) {
                    const double ov = __shfl_xor(bv, off);
                    const int    oi = __shfl_xor(bi, off);
                    const float  og = __shfl_xor(bg, off);
                    if (ov > bv || (ov == bv && oi < bi)) { bv = ov; bi = oi; bg = og; }
                }
                sumtop += bg;
                if (lane == j)  { myv = bg; myi = bi; }
                if (lane == bi) work = -1e300;
            }
            if (lane < 8) {
                out_gates[(size_t)grow * 8 + lane] = myv / sumtop;
                out_idx  [(size_t)grow * 8 + lane] = (float)myi;
            }
        }
    }
}

// ---------------- Kernel D: loss finalize ----------------
__global__ __launch_bounds__(256) void router_finalize(
    const float* __restrict__ ws_imp, const float* __restrict__ ws_load,
    float* __restrict__ loss_out)
{
    __shared__ float si[4][NEXP], sl[4][NEXP];
    const int tid = threadIdx.x;
    const int e = tid & 63;
    const int g = tid >> 6;
    float a = 0.f, b = 0.f;
    for (int blk = g * 64; blk < g * 64 + 64; ++blk) {
        a += ws_imp[blk * NEXP + e];
        b += ws_load[blk * NEXP + e];
    }
    si[g][e] = a; sl[g][e] = b;
    __syncthreads();
    if (tid < 64) {
        const float imp = (si[0][e] + si[1][e] + si[2][e] + si[3][e]) / (float)NROWS;
        const float ld  = (sl[0][e] + sl[1][e] + sl[2][e] + sl[3][e]) / (float)(NROWS * 8);
        float term = imp * ld;
        #pragma unroll
        for (int off = 32; off; off >>= 1) term += __shfl_xor(term, off);
        if (e == 0) *loss_out = term * (float)NEXP;
    }
}

extern "C" void kernel_launch(void* const* d_in, const int* in_sizes, int n_in,
                              void* d_out, int out_size, void* d_ws, size_t ws_size,
                              hipStream_t stream) {
    const float* x     = (const float*)d_in[0];
    const float* Wg    = (const float*)d_in[1];
    const float* noise = (const float*)d_in[2];
    float* out       = (float*)d_out;
    float* out_gates = out;
    float* out_idx   = out + (size_t)NROWS * 8;
    float* loss_out  = out + (size_t)2 * NROWS * 8;

    // choose K-split to fit workspace: partials = 256*KS*4096 floats (+192KB misc)
    const size_t misc = (size_t)3 * 16384 * 4;
    int ks_shift = 3;
    while (ks_shift > 0 &&
           ((size_t)256 * (1u << ks_shift) * 4096 * 4 + misc) > ws_size)
        --ks_shift;
    const int KS = 1 << ks_shift;

    float* partials = (float*)d_ws;
    float* ws_imp   = partials + (size_t)256 * KS * 4096;
    float* ws_load  = ws_imp + 256 * NEXP;
    int*   flags    = (int*)(ws_load + 256 * NEXP);

    gemm_partial   <<<256 * KS, 64,  0, stream>>>(x, Wg, partials, ks_shift);
    combine_epilogue<<<256,     256, 0, stream>>>(partials, noise, out_gates, out_idx,
                                                  ws_imp, ws_load, flags, ks_shift);
    repair_rows    <<<256,      256, 0, stream>>>(x, Wg, noise, flags, out_gates, out_idx);
    router_finalize<<<1,        256, 0, stream>>>(ws_imp, ws_load, loss_out);
}

// Round 4
// 491.523 us; speedup vs baseline: 1.3396x; 1.3396x over previous
//
#include <hip/hip_runtime.h>

#define NROWS 16384
#define DDIM  4096
#define NEXP  64
#define TAU   1e-3f

// ---------------- Kernel A: fp32 partial GEMM ----------------
// 256 threads (4 waves), BM=64 rows x 64 experts, DK=32 K-tile.
// grid = 256*KS; block (rb,kq) covers k-range [kq*kper, (kq+1)*kper).
// LDS xT[k][row] transposed (a-reads b128 conflict-free, writes 2-way-free),
// Wt[k][e] linear. Register double-buffer: px[2]+pw[2] f4 = 16 VGPR.
// Per-thread 4x4 acc. ~60 VGPR total -> no spills (R3's failure mode).
__global__ __launch_bounds__(256) void gemm_partial(
    const float* __restrict__ x, const float* __restrict__ Wg,
    float* __restrict__ partials, int ks_shift)
{
    __shared__ float xT[32 * 64];   // 8 KB  [k][row]
    __shared__ float Wt[32 * 64];   // 8 KB  [k][e]

    const int tid = threadIdx.x;
    const int rg  = tid >> 4;       // 0..15: rows rg*4..+3
    const int cg  = tid & 15;       // 0..15: cols cg*4..+3
    const int KS   = 1 << ks_shift;
    const int kper = DDIM >> ks_shift;
    const int T    = kper >> 5;
    const int rb   = (int)blockIdx.x >> ks_shift;
    const int kq   = (int)blockIdx.x & (KS - 1);

    const int srow = tid & 63;      // staging: this thread stages x row srow
    const int wv   = tid >> 6;      // wave id: covers f4-cols {2wv, 2wv+1}

    const float* xbase = x + (size_t)(rb * 64 + srow) * DDIM + kq * kper;
    const float* wbase = Wg + (size_t)(kq * kper) * NEXP;

    float4 px[2], pw[2];
    px[0] = *(const float4*)(xbase + (wv * 2 + 0) * 4);
    px[1] = *(const float4*)(xbase + (wv * 2 + 1) * 4);
    pw[0] = *(const float4*)(wbase + (size_t)tid * 4);
    pw[1] = *(const float4*)(wbase + (size_t)(tid + 256) * 4);

    float acc[4][4];
    #pragma unroll
    for (int i = 0; i < 4; ++i)
        #pragma unroll
        for (int j = 0; j < 4; ++j) acc[i][j] = 0.f;

    for (int t = 0; t < T; ++t) {
        __syncthreads();                         // prev tile fully consumed
        #pragma unroll
        for (int h = 0; h < 2; ++h) {            // stage regs -> LDS
            const int k0 = (wv * 2 + h) * 4;     // k uniform per wave-instr
            xT[(k0 + 0) * 64 + srow] = px[h].x;
            xT[(k0 + 1) * 64 + srow] = px[h].y;
            xT[(k0 + 2) * 64 + srow] = px[h].z;
            xT[(k0 + 3) * 64 + srow] = px[h].w;
            *(float4*)&Wt[(tid + 256 * h) * 4] = pw[h];
        }
        __syncthreads();
        if (t + 1 < T) {                         // prefetch next tile
            const float* xp = xbase + (t + 1) * 32;
            const float* wp = wbase + (size_t)(t + 1) * 32 * NEXP;
            px[0] = *(const float4*)(xp + (wv * 2 + 0) * 4);
            px[1] = *(const float4*)(xp + (wv * 2 + 1) * 4);
            pw[0] = *(const float4*)(wp + (size_t)tid * 4);
            pw[1] = *(const float4*)(wp + (size_t)(tid + 256) * 4);
        }
        #pragma unroll 8
        for (int k = 0; k < 32; ++k) {
            const float4 a = *(const float4*)&xT[k * 64 + rg * 4];
            const float4 b = *(const float4*)&Wt[k * 64 + cg * 4];
            acc[0][0] = fmaf(a.x, b.x, acc[0][0]);
            acc[0][1] = fmaf(a.x, b.y, acc[0][1]);
            acc[0][2] = fmaf(a.x, b.z, acc[0][2]);
            acc[0][3] = fmaf(a.x, b.w, acc[0][3]);
            acc[1][0] = fmaf(a.y, b.x, acc[1][0]);
            acc[1][1] = fmaf(a.y, b.y, acc[1][1]);
            acc[1][2] = fmaf(a.y, b.z, acc[1][2]);
            acc[1][3] = fmaf(a.y, b.w, acc[1][3]);
            acc[2][0] = fmaf(a.z, b.x, acc[2][0]);
            acc[2][1] = fmaf(a.z, b.y, acc[2][1]);
            acc[2][2] = fmaf(a.z, b.z, acc[2][2]);
            acc[2][3] = fmaf(a.z, b.w, acc[2][3]);
            acc[3][0] = fmaf(a.w, b.x, acc[3][0]);
            acc[3][1] = fmaf(a.w, b.y, acc[3][1]);
            acc[3][2] = fmaf(a.w, b.z, acc[3][2]);
            acc[3][3] = fmaf(a.w, b.w, acc[3][3]);
        }
    }

    float* po = partials + ((size_t)(rb << ks_shift) + kq) * (64 * 64);
    #pragma unroll
    for (int i = 0; i < 4; ++i)
        *(float4*)(po + (rg * 4 + i) * 64 + cg * 4) =
            make_float4(acc[i][0], acc[i][1], acc[i][2], acc[i][3]);
}

// ---------------- Kernel B: combine + softmax + top-9 + flags ----------------
__global__ __launch_bounds__(256) void combine_epilogue(
    const float* __restrict__ partials, const float* __restrict__ noise,
    float* __restrict__ out_gates, float* __restrict__ out_idx,
    float* __restrict__ ws_imp, float* __restrict__ ws_load,
    int* __restrict__ flags, int ks_shift)
{
    __shared__ float red[4][NEXP];
    const int tid = threadIdx.x, lane = tid & 63, w = tid >> 6;
    const int rb = blockIdx.x;
    const int KS = 1 << ks_shift;

    float impacc = 0.f, loadacc = 0.f;
    for (int rr = 0; rr < 16; ++rr) {
        const int row = w * 16 + rr;
        const int grow = rb * 64 + row;
        float v = noise[(size_t)grow * NEXP + lane];
        const float* pp = partials + ((size_t)(rb << ks_shift)) * 4096 + row * 64 + lane;
        for (int q = 0; q < KS; ++q) v += pp[(size_t)q * 4096];   // fixed order

        float m = v;
        #pragma unroll
        for (int off = 32; off; off >>= 1) m = fmaxf(m, __shfl_xor(m, off));
        const float ex = __expf(v - m);
        float s = ex;
        #pragma unroll
        for (int off = 32; off; off >>= 1) s += __shfl_xor(s, off);
        const float g = ex * (1.0f / s);
        impacc += g;

        // top-9 keyed on fp32 logit v (monotonic with gates); flag near-ties
        float work = v, vprev = 0.f;
        float myv = 0.f, sumtop = 0.f;
        int myi = 0, mine = 0, flg = 0;
        #pragma unroll
        for (int j = 0; j < 9; ++j) {
            float bv = work, bg = g; int bi = lane;
            #pragma unroll
            for (int off = 32; off; off >>= 1) {
                const float ov = __shfl_xor(bv, off);
                const int   oi = __shfl_xor(bi, off);
                const float og = __shfl_xor(bg, off);
                if (ov > bv || (ov == bv && oi < bi)) { bv = ov; bi = oi; bg = og; }
            }
            if (j > 0) flg |= (vprev - bv < TAU) ? 1 : 0;
            vprev = bv;
            if (j < 8) {
                sumtop += bg;
                if (lane == j)  { myv = bg; myi = bi; }
                if (lane == bi) { work = -3e38f; mine = 1; }
            }
        }
        loadacc += (float)mine;

        if (lane < 8) {
            out_gates[(size_t)grow * 8 + lane] = myv / sumtop;
            out_idx  [(size_t)grow * 8 + lane] = (float)myi;
        }
        if (lane == 0) flags[grow] = flg;
    }

    red[w][lane] = impacc;
    __syncthreads();
    if (w == 0)
        ws_imp[(size_t)rb * NEXP + lane] =
            red[0][lane] + red[1][lane] + red[2][lane] + red[3][lane];
    __syncthreads();
    red[w][lane] = loadacc;
    __syncthreads();
    if (w == 0)
        ws_load[(size_t)rb * NEXP + lane] =
            red[0][lane] + red[1][lane] + red[2][lane] + red[3][lane];
}

// ---------------- Kernel C: fp64 repair of flagged rows ----------------
__global__ __launch_bounds__(256) void repair_rows(
    const float* __restrict__ x, const float* __restrict__ Wg,
    const float* __restrict__ noise, const int* __restrict__ flags,
    float* __restrict__ out_gates, float* __restrict__ out_idx)
{
    __shared__ float xr[DDIM];          // 16 KB
    __shared__ double red64[4][NEXP];   // 2 KB
    const int tid = threadIdx.x, lane = tid & 63, w = tid >> 6;

    for (int r = 0; r < 64; ++r) {
        const int grow = (int)blockIdx.x * 64 + r;
        if (!flags[grow]) continue;     // block-uniform branch
        __syncthreads();                // prior row's LDS fully consumed
        #pragma unroll
        for (int i = 0; i < 4; ++i)
            ((float4*)xr)[tid + 256 * i] =
                ((const float4*)(x + (size_t)grow * DDIM))[tid + 256 * i];
        __syncthreads();

        // wave w covers k-chunk w*1024; lane = expert; 4 chains for latency
        double a0 = 0, a1 = 0, a2 = 0, a3 = 0;
        const float* wp = Wg + (size_t)(w * 1024) * NEXP + lane;
        const float* xp = xr + w * 1024;
        for (int k = 0; k < 1024; k += 4) {
            a0 = fma((double)xp[k + 0], (double)wp[(size_t)(k + 0) * NEXP], a0);
            a1 = fma((double)xp[k + 1], (double)wp[(size_t)(k + 1) * NEXP], a1);
            a2 = fma((double)xp[k + 2], (double)wp[(size_t)(k + 2) * NEXP], a2);
            a3 = fma((double)xp[k + 3], (double)wp[(size_t)(k + 3) * NEXP], a3);
        }
        red64[w][lane] = ((a0 + a1) + a2) + a3;
        __syncthreads();

        if (w == 0) {
            const double v64 = (((red64[0][lane] + red64[1][lane]) + red64[2][lane])
                                + red64[3][lane]) + (double)noise[(size_t)grow * NEXP + lane];
            double m = v64;
            #pragma unroll
            for (int off = 32; off; off >>= 1) m = fmax(m, __shfl_xor(m, off));
            const float ex = __expf((float)(v64 - m));
            float s = ex;
            #pragma unroll
            for (int off = 32; off; off >>= 1) s += __shfl_xor(s, off);
            const float g = ex * (1.0f / s);

            double work = v64;
            float myv = 0.f, sumtop = 0.f, bg;
            int myi = 0;
            #pragma unroll
            for (int j = 0; j < 8; ++j) {
                double bv = work; int bi = lane; bg = g;
                #pragma unroll
                for (int off = 32; off; off >>= 1) {
                    const double ov = __shfl_xor(bv, off);
                    const int    oi = __shfl_xor(bi, off);
                    const float  og = __shfl_xor(bg, off);
                    if (ov > bv || (ov == bv && oi < bi)) { bv = ov; bi = oi; bg = og; }
                }
                sumtop += bg;
                if (lane == j)  { myv = bg; myi = bi; }
                if (lane == bi) work = -1e300;
            }
            if (lane < 8) {
                out_gates[(size_t)grow * 8 + lane] = myv / sumtop;
                out_idx  [(size_t)grow * 8 + lane] = (float)myi;
            }
        }
    }
}

// ---------------- Kernel D: loss finalize ----------------
__global__ __launch_bounds__(256) void router_finalize(
    const float* __restrict__ ws_imp, const float* __restrict__ ws_load,
    float* __restrict__ loss_out)
{
    __shared__ float si[4][NEXP], sl[4][NEXP];
    const int tid = threadIdx.x;
    const int e = tid & 63;
    const int g = tid >> 6;
    float a = 0.f, b = 0.f;
    for (int blk = g * 64; blk < g * 64 + 64; ++blk) {
        a += ws_imp[blk * NEXP + e];
        b += ws_load[blk * NEXP + e];
    }
    si[g][e] = a; sl[g][e] = b;
    __syncthreads();
    if (tid < 64) {
        const float imp = (si[0][e] + si[1][e] + si[2][e] + si[3][e]) / (float)NROWS;
        const float ld  = (sl[0][e] + sl[1][e] + sl[2][e] + sl[3][e]) / (float)(NROWS * 8);
        float term = imp * ld;
        #pragma unroll
        for (int off = 32; off; off >>= 1) term += __shfl_xor(term, off);
        if (e == 0) *loss_out = term * (float)NEXP;
    }
}

extern "C" void kernel_launch(void* const* d_in, const int* in_sizes, int n_in,
                              void* d_out, int out_size, void* d_ws, size_t ws_size,
                              hipStream_t stream) {
    const float* x     = (const float*)d_in[0];
    const float* Wg    = (const float*)d_in[1];
    const float* noise = (const float*)d_in[2];
    float* out       = (float*)d_out;
    float* out_gates = out;
    float* out_idx   = out + (size_t)NROWS * 8;
    float* loss_out  = out + (size_t)2 * NROWS * 8;

    // choose K-split to fit workspace: partials = 256*KS*4096 floats (+misc)
    const size_t misc = (size_t)3 * 16384 * 4;
    int ks_shift = 3;
    while (ks_shift > 0 &&
           ((size_t)256 * (1u << ks_shift) * 4096 * 4 + misc) > ws_size)
        --ks_shift;
    const int KS = 1 << ks_shift;

    float* partials = (float*)d_ws;
    float* ws_imp   = partials + (size_t)256 * KS * 4096;
    float* ws_load  = ws_imp + 256 * NEXP;
    int*   flags    = (int*)(ws_load + 256 * NEXP);

    gemm_partial    <<<256 * KS, 256, 0, stream>>>(x, Wg, partials, ks_shift);
    combine_epilogue<<<256,      256, 0, stream>>>(partials, noise, out_gates, out_idx,
                                                   ws_imp, ws_load, flags, ks_shift);
    repair_rows     <<<256,      256, 0, stream>>>(x, Wg, noise, flags, out_gates, out_idx);
    router_finalize <<<1,        256, 0, stream>>>(ws_imp, ws_load, loss_out);
}

// Round 5
// 238.529 us; speedup vs baseline: 2.7604x; 2.0606x over previous
//
#include <hip/hip_runtime.h>

#define NROWS 16384
#define DDIM  4096
#define NEXP  64
#define TAU   1e-3f
#define CB    2048        // combine blocks (8 rows each)
#define RB    2048        // repair worker blocks

// ---------------- Kernel A: fp32 partial GEMM ----------------
// 256 threads (4 waves), 64 rows x 64 experts, DK=32 K-tile, grid 256*KS.
// LDS xT[k][row] transposed, Wt[k][e] linear; register double-buffer.
// ~60 VGPR, no spills. Also zeroes the repair-worklist counter (block 0).
__global__ __launch_bounds__(256) void gemm_partial(
    const float* __restrict__ x, const float* __restrict__ Wg,
    float* __restrict__ partials, int* __restrict__ counter, int ks_shift)
{
    if (blockIdx.x == 0 && threadIdx.x == 0) *counter = 0;

    __shared__ float xT[32 * 64];   // 8 KB  [k][row]
    __shared__ float Wt[32 * 64];   // 8 KB  [k][e]

    const int tid = threadIdx.x;
    const int rg  = tid >> 4;       // 0..15: rows rg*4..+3
    const int cg  = tid & 15;       // 0..15: cols cg*4..+3
    const int KS   = 1 << ks_shift;
    const int kper = DDIM >> ks_shift;
    const int T    = kper >> 5;
    const int rb   = (int)blockIdx.x >> ks_shift;
    const int kq   = (int)blockIdx.x & (KS - 1);

    const int srow = tid & 63;      // staging: this thread stages x row srow
    const int wv   = tid >> 6;      // wave id: covers f4-cols {2wv, 2wv+1}

    const float* xbase = x + (size_t)(rb * 64 + srow) * DDIM + kq * kper;
    const float* wbase = Wg + (size_t)(kq * kper) * NEXP;

    float4 px[2], pw[2];
    px[0] = *(const float4*)(xbase + (wv * 2 + 0) * 4);
    px[1] = *(const float4*)(xbase + (wv * 2 + 1) * 4);
    pw[0] = *(const float4*)(wbase + (size_t)tid * 4);
    pw[1] = *(const float4*)(wbase + (size_t)(tid + 256) * 4);

    float acc[4][4];
    #pragma unroll
    for (int i = 0; i < 4; ++i)
        #pragma unroll
        for (int j = 0; j < 4; ++j) acc[i][j] = 0.f;

    for (int t = 0; t < T; ++t) {
        __syncthreads();
        #pragma unroll
        for (int h = 0; h < 2; ++h) {            // stage regs -> LDS
            const int k0 = (wv * 2 + h) * 4;
            xT[(k0 + 0) * 64 + srow] = px[h].x;
            xT[(k0 + 1) * 64 + srow] = px[h].y;
            xT[(k0 + 2) * 64 + srow] = px[h].z;
            xT[(k0 + 3) * 64 + srow] = px[h].w;
            *(float4*)&Wt[(tid + 256 * h) * 4] = pw[h];
        }
        __syncthreads();
        if (t + 1 < T) {                         // prefetch next tile
            const float* xp = xbase + (t + 1) * 32;
            const float* wp = wbase + (size_t)(t + 1) * 32 * NEXP;
            px[0] = *(const float4*)(xp + (wv * 2 + 0) * 4);
            px[1] = *(const float4*)(xp + (wv * 2 + 1) * 4);
            pw[0] = *(const float4*)(wp + (size_t)tid * 4);
            pw[1] = *(const float4*)(wp + (size_t)(tid + 256) * 4);
        }
        #pragma unroll 8
        for (int k = 0; k < 32; ++k) {
            const float4 a = *(const float4*)&xT[k * 64 + rg * 4];
            const float4 b = *(const float4*)&Wt[k * 64 + cg * 4];
            acc[0][0] = fmaf(a.x, b.x, acc[0][0]);
            acc[0][1] = fmaf(a.x, b.y, acc[0][1]);
            acc[0][2] = fmaf(a.x, b.z, acc[0][2]);
            acc[0][3] = fmaf(a.x, b.w, acc[0][3]);
            acc[1][0] = fmaf(a.y, b.x, acc[1][0]);
            acc[1][1] = fmaf(a.y, b.y, acc[1][1]);
            acc[1][2] = fmaf(a.y, b.z, acc[1][2]);
            acc[1][3] = fmaf(a.y, b.w, acc[1][3]);
            acc[2][0] = fmaf(a.z, b.x, acc[2][0]);
            acc[2][1] = fmaf(a.z, b.y, acc[2][1]);
            acc[2][2] = fmaf(a.z, b.z, acc[2][2]);
            acc[2][3] = fmaf(a.z, b.w, acc[2][3]);
            acc[3][0] = fmaf(a.w, b.x, acc[3][0]);
            acc[3][1] = fmaf(a.w, b.y, acc[3][1]);
            acc[3][2] = fmaf(a.w, b.z, acc[3][2]);
            acc[3][3] = fmaf(a.w, b.w, acc[3][3]);
        }
    }

    float* po = partials + ((size_t)(rb << ks_shift) + kq) * (64 * 64);
    #pragma unroll
    for (int i = 0; i < 4; ++i)
        *(float4*)(po + (rg * 4 + i) * 64 + cg * 4) =
            make_float4(acc[i][0], acc[i][1], acc[i][2], acc[i][3]);
}

// ---------------- Kernel B: combine + softmax + top-9 + worklist ----------------
// grid CB=2048 blocks, 8 rows/block (2 per wave) -> 8 blocks/CU.
__global__ __launch_bounds__(256) void combine_epilogue(
    const float* __restrict__ partials, const float* __restrict__ noise,
    float* __restrict__ out_gates, float* __restrict__ out_idx,
    float* __restrict__ ws_imp, float* __restrict__ ws_load,
    int* __restrict__ worklist, int* __restrict__ counter, int ks_shift)
{
    __shared__ float red[4][NEXP];
    const int tid = threadIdx.x, lane = tid & 63, w = tid >> 6;
    const int KS = 1 << ks_shift;

    float impacc = 0.f, loadacc = 0.f;
    #pragma unroll
    for (int rr = 0; rr < 2; ++rr) {
        const int grow = (int)blockIdx.x * 8 + w * 2 + rr;
        const int rb = grow >> 6, row = grow & 63;
        float v = noise[(size_t)grow * NEXP + lane];
        const float* pp = partials + ((size_t)(rb << ks_shift)) * 4096 + row * 64 + lane;
        for (int q = 0; q < KS; ++q) v += pp[(size_t)q * 4096];   // fixed order

        float m = v;
        #pragma unroll
        for (int off = 32; off; off >>= 1) m = fmaxf(m, __shfl_xor(m, off));
        const float ex = __expf(v - m);
        float s = ex;
        #pragma unroll
        for (int off = 32; off; off >>= 1) s += __shfl_xor(s, off);
        const float g = ex * (1.0f / s);
        impacc += g;

        // top-9 keyed on fp32 logit v; flag near-ties for fp64 repair
        float work = v, vprev = 0.f;
        float myv = 0.f, sumtop = 0.f;
        int myi = 0, mine = 0, flg = 0;
        #pragma unroll
        for (int j = 0; j < 9; ++j) {
            float bv = work, bg = g; int bi = lane;
            #pragma unroll
            for (int off = 32; off; off >>= 1) {
                const float ov = __shfl_xor(bv, off);
                const int   oi = __shfl_xor(bi, off);
                const float og = __shfl_xor(bg, off);
                if (ov > bv || (ov == bv && oi < bi)) { bv = ov; bi = oi; bg = og; }
            }
            if (j > 0) flg |= (vprev - bv < TAU) ? 1 : 0;
            vprev = bv;
            if (j < 8) {
                sumtop += bg;
                if (lane == j)  { myv = bg; myi = bi; }
                if (lane == bi) { work = -3e38f; mine = 1; }
            }
        }
        loadacc += (float)mine;

        if (lane < 8) {
            out_gates[(size_t)grow * 8 + lane] = myv / sumtop;
            out_idx  [(size_t)grow * 8 + lane] = (float)myi;
        }
        if (lane == 0 && flg) {
            const int pos = atomicAdd(counter, 1);
            worklist[pos] = grow;
        }
    }

    red[w][lane] = impacc;
    __syncthreads();
    if (w == 0)
        ws_imp[(size_t)blockIdx.x * NEXP + lane] =
            red[0][lane] + red[1][lane] + red[2][lane] + red[3][lane];
    __syncthreads();
    red[w][lane] = loadacc;
    __syncthreads();
    if (w == 0)
        ws_load[(size_t)blockIdx.x * NEXP + lane] =
            red[0][lane] + red[1][lane] + red[2][lane] + red[3][lane];
}

// ---------------- Kernel C: fp64 repair (worklist) + loss finalize ----------------
// blocks 0..RB-1: repair rows from worklist. block RB: loss finalize.
__global__ __launch_bounds__(256) void repair_finalize(
    const float* __restrict__ x, const float* __restrict__ Wg,
    const float* __restrict__ noise, const int* __restrict__ worklist,
    const int* __restrict__ counter, const float* __restrict__ ws_imp,
    const float* __restrict__ ws_load, float* __restrict__ out_gates,
    float* __restrict__ out_idx, float* __restrict__ loss_out)
{
    const int tid = threadIdx.x, lane = tid & 63, w = tid >> 6;

    if (blockIdx.x == RB) {                     // ---- loss finalize ----
        __shared__ float si[4][NEXP], sl[4][NEXP];
        float a = 0.f, b = 0.f;
        for (int blk = w * (CB / 4); blk < (w + 1) * (CB / 4); ++blk) {
            a += ws_imp[(size_t)blk * NEXP + lane];
            b += ws_load[(size_t)blk * NEXP + lane];
        }
        si[w][lane] = a; sl[w][lane] = b;
        __syncthreads();
        if (w == 0) {
            const float imp = (si[0][lane] + si[1][lane] + si[2][lane] + si[3][lane])
                              / (float)NROWS;
            const float ld  = (sl[0][lane] + sl[1][lane] + sl[2][lane] + sl[3][lane])
                              / (float)(NROWS * 8);
            float term = imp * ld;
            #pragma unroll
            for (int off = 32; off; off >>= 1) term += __shfl_xor(term, off);
            if (lane == 0) *loss_out = term * (float)NEXP;
        }
        return;
    }

    // ---- repair: ~1 flagged row per block ----
    __shared__ float xr[DDIM];          // 16 KB
    __shared__ double red64[4][NEXP];   // 2 KB
    const int count = *counter;

    for (int i = (int)blockIdx.x; i < count; i += RB) {
        const int grow = worklist[i];
        __syncthreads();                // prior iteration's LDS consumed
        #pragma unroll
        for (int q = 0; q < 4; ++q)
            ((float4*)xr)[tid + 256 * q] =
                ((const float4*)(x + (size_t)grow * DDIM))[tid + 256 * q];
        __syncthreads();

        // wave w covers k-chunk w*1024; lane = expert; 4 chains
        double a0 = 0, a1 = 0, a2 = 0, a3 = 0;
        const float* wp = Wg + (size_t)(w * 1024) * NEXP + lane;
        const float* xp = xr + w * 1024;
        for (int k = 0; k < 1024; k += 4) {
            a0 = fma((double)xp[k + 0], (double)wp[(size_t)(k + 0) * NEXP], a0);
            a1 = fma((double)xp[k + 1], (double)wp[(size_t)(k + 1) * NEXP], a1);
            a2 = fma((double)xp[k + 2], (double)wp[(size_t)(k + 2) * NEXP], a2);
            a3 = fma((double)xp[k + 3], (double)wp[(size_t)(k + 3) * NEXP], a3);
        }
        red64[w][lane] = ((a0 + a1) + a2) + a3;
        __syncthreads();

        if (w == 0) {
            const double v64 = (((red64[0][lane] + red64[1][lane]) + red64[2][lane])
                                + red64[3][lane]) + (double)noise[(size_t)grow * NEXP + lane];
            double m = v64;
            #pragma unroll
            for (int off = 32; off; off >>= 1) m = fmax(m, __shfl_xor(m, off));
            const float ex = __expf((float)(v64 - m));
            float s = ex;
            #pragma unroll
            for (int off = 32; off; off >>= 1) s += __shfl_xor(s, off);
            const float g = ex * (1.0f / s);

            double work = v64;
            float myv = 0.f, sumtop = 0.f, bg;
            int myi = 0;
            #pragma unroll
            for (int j = 0; j < 8; ++j) {
                double bv = work; int bi = lane; bg = g;
                #pragma unroll
                for (int off = 32; off; off >>= 1) {
                    const double ov = __shfl_xor(bv, off);
                    const int    oi = __shfl_xor(bi, off);
                    const float  og = __shfl_xor(bg, off);
                    if (ov > bv || (ov == bv && oi < bi)) { bv = ov; bi = oi; bg = og; }
                }
                sumtop += bg;
                if (lane == j)  { myv = bg; myi = bi; }
                if (lane == bi) work = -1e300;
            }
            if (lane < 8) {
                out_gates[(size_t)grow * 8 + lane] = myv / sumtop;
                out_idx  [(size_t)grow * 8 + lane] = (float)myi;
            }
        }
    }
}

extern "C" void kernel_launch(void* const* d_in, const int* in_sizes, int n_in,
                              void* d_out, int out_size, void* d_ws, size_t ws_size,
                              hipStream_t stream) {
    const float* x     = (const float*)d_in[0];
    const float* Wg    = (const float*)d_in[1];
    const float* noise = (const float*)d_in[2];
    float* out       = (float*)d_out;
    float* out_gates = out;
    float* out_idx   = out + (size_t)NROWS * 8;
    float* loss_out  = out + (size_t)2 * NROWS * 8;

    // ws layout: partials | ws_imp[CB*64] | ws_load[CB*64] | worklist[16384] | counter
    const size_t misc = ((size_t)2 * CB * NEXP + NROWS + 64) * 4;
    int ks_shift = 3;
    while (ks_shift > 0 &&
           ((size_t)256 * (1u << ks_shift) * 4096 * 4 + misc) > ws_size)
        --ks_shift;
    const int KS = 1 << ks_shift;

    float* partials = (float*)d_ws;
    float* ws_imp   = partials + (size_t)256 * KS * 4096;
    float* ws_load  = ws_imp + (size_t)CB * NEXP;
    int*   worklist = (int*)(ws_load + (size_t)CB * NEXP);
    int*   counter  = worklist + NROWS;

    gemm_partial    <<<256 * KS, 256, 0, stream>>>(x, Wg, partials, counter, ks_shift);
    combine_epilogue<<<CB,       256, 0, stream>>>(partials, noise, out_gates, out_idx,
                                                   ws_imp, ws_load, worklist, counter,
                                                   ks_shift);
    repair_finalize <<<RB + 1,   256, 0, stream>>>(x, Wg, noise, worklist, counter,
                                                   ws_imp, ws_load, out_gates, out_idx,
                                                   loss_out);
}

// Round 6
// 212.163 us; speedup vs baseline: 3.1034x; 1.1243x over previous
//
#include <hip/hip_runtime.h>

#define NROWS 16384
#define DDIM  4096
#define NEXP  64
#define TAU   1e-3f
#define CB    2048        // combine blocks (8 rows each)
#define RB    2048        // repair worker blocks
#define RBLK  64          // reduce_stage blocks

// ---------------- Kernel A: fp32 partial GEMM ----------------
// 256 threads (4 waves), BM=256 rows x 64 experts, DK=16 K-tile.
// Per-thread 8x8 tile -> 1 B LDS per FMA (R5's 4x4 was 2 B/FMA and
// LDS-throughput-bound at 163us). grid = 64*KS.
// xT[k][256] transposed (scalar writes 2-way-free; a-reads b128 2-way +
// 8-lane broadcast), Wt[k][64] linear (b-reads 2-way + broadcast).
// Register prefetch: 4 f4 x + 1 f4 W = 20 VGPR; acc 64 -> ~120 total.
__global__ __launch_bounds__(256) void gemm_partial(
    const float* __restrict__ x, const float* __restrict__ Wg,
    float* __restrict__ partials, int* __restrict__ counter, int ks_shift)
{
    if (blockIdx.x == 0 && threadIdx.x == 0) *counter = 0;

    __shared__ float xT[16 * 256];  // 16 KB  [k][row]
    __shared__ float Wt[16 * 64];   //  4 KB  [k][e]

    const int tid = threadIdx.x;
    const int rg  = tid >> 3;       // 0..31: rows rg*8..+7 (wave-local 8 values)
    const int cg  = tid & 7;        // 0..7 : cols cg*8..+7
    const int KS   = 1 << ks_shift;
    const int kper = DDIM >> ks_shift;
    const int T    = kper >> 4;
    const int rb   = (int)blockIdx.x >> ks_shift;
    const int kq   = (int)blockIdx.x & (KS - 1);

    const float* xbase = x + (size_t)(rb * 256 + tid) * DDIM + kq * kper;
    const float* wbase = Wg + (size_t)(kq * kper) * NEXP;

    float4 px[4], pw;
    #pragma unroll
    for (int q = 0; q < 4; ++q)
        px[q] = *(const float4*)(xbase + q * 4);
    pw = *(const float4*)(wbase + (size_t)tid * 4);

    float acc[8][8];
    #pragma unroll
    for (int i = 0; i < 8; ++i)
        #pragma unroll
        for (int j = 0; j < 8; ++j) acc[i][j] = 0.f;

    for (int t = 0; t < T; ++t) {
        __syncthreads();                         // prev tile fully consumed
        #pragma unroll
        for (int q = 0; q < 4; ++q) {            // stage x row tid, k = q*4+j
            xT[(q * 4 + 0) * 256 + tid] = px[q].x;
            xT[(q * 4 + 1) * 256 + tid] = px[q].y;
            xT[(q * 4 + 2) * 256 + tid] = px[q].z;
            xT[(q * 4 + 3) * 256 + tid] = px[q].w;
        }
        *(float4*)&Wt[tid * 4] = pw;             // 256 f4 = whole W tile
        __syncthreads();
        if (t + 1 < T) {                         // prefetch next tile
            const float* xp = xbase + (t + 1) * 16;
            const float* wp = wbase + (size_t)(t + 1) * 16 * NEXP;
            #pragma unroll
            for (int q = 0; q < 4; ++q)
                px[q] = *(const float4*)(xp + q * 4);
            pw = *(const float4*)(wp + (size_t)tid * 4);
        }
        #pragma unroll
        for (int k = 0; k < 16; ++k) {
            const float4 a0 = *(const float4*)&xT[k * 256 + rg * 8];
            const float4 a1 = *(const float4*)&xT[k * 256 + rg * 8 + 4];
            const float4 b0 = *(const float4*)&Wt[k * 64 + cg * 8];
            const float4 b1 = *(const float4*)&Wt[k * 64 + cg * 8 + 4];
            const float a[8] = {a0.x, a0.y, a0.z, a0.w, a1.x, a1.y, a1.z, a1.w};
            const float b[8] = {b0.x, b0.y, b0.z, b0.w, b1.x, b1.y, b1.z, b1.w};
            #pragma unroll
            for (int i = 0; i < 8; ++i)
                #pragma unroll
                for (int j = 0; j < 8; ++j)
                    acc[i][j] = fmaf(a[i], b[j], acc[i][j]);
        }
    }

    float* po = partials + ((size_t)(rb << ks_shift) + kq) * (256 * 64);
    #pragma unroll
    for (int i = 0; i < 8; ++i) {
        *(float4*)(po + (rg * 8 + i) * 64 + cg * 8) =
            make_float4(acc[i][0], acc[i][1], acc[i][2], acc[i][3]);
        *(float4*)(po + (rg * 8 + i) * 64 + cg * 8 + 4) =
            make_float4(acc[i][4], acc[i][5], acc[i][6], acc[i][7]);
    }
}

// ---------------- Kernel B: combine + softmax + top-9 + worklist ----------------
// grid CB=2048 blocks, 8 rows/block (2 per wave).
__global__ __launch_bounds__(256) void combine_epilogue(
    const float* __restrict__ partials, const float* __restrict__ noise,
    float* __restrict__ out_gates, float* __restrict__ out_idx,
    float* __restrict__ ws_imp, float* __restrict__ ws_load,
    int* __restrict__ worklist, int* __restrict__ counter, int ks_shift)
{
    __shared__ float red[4][NEXP];
    const int tid = threadIdx.x, lane = tid & 63, w = tid >> 6;
    const int KS = 1 << ks_shift;

    float impacc = 0.f, loadacc = 0.f;
    #pragma unroll
    for (int rr = 0; rr < 2; ++rr) {
        const int grow = (int)blockIdx.x * 8 + w * 2 + rr;
        const int rb = grow >> 8, row = grow & 255;     // BM=256 partial tiles
        float v = noise[(size_t)grow * NEXP + lane];
        const float* pp = partials + ((size_t)(rb << ks_shift)) * (256 * 64)
                          + row * 64 + lane;
        for (int q = 0; q < KS; ++q) v += pp[(size_t)q * (256 * 64)]; // fixed order

        float m = v;
        #pragma unroll
        for (int off = 32; off; off >>= 1) m = fmaxf(m, __shfl_xor(m, off));
        const float ex = __expf(v - m);
        float s = ex;
        #pragma unroll
        for (int off = 32; off; off >>= 1) s += __shfl_xor(s, off);
        const float g = ex * (1.0f / s);
        impacc += g;

        // top-9 keyed on fp32 logit v; flag near-ties for fp64 repair
        float work = v, vprev = 0.f;
        float myv = 0.f, sumtop = 0.f;
        int myi = 0, mine = 0, flg = 0;
        #pragma unroll
        for (int j = 0; j < 9; ++j) {
            float bv = work, bg = g; int bi = lane;
            #pragma unroll
            for (int off = 32; off; off >>= 1) {
                const float ov = __shfl_xor(bv, off);
                const int   oi = __shfl_xor(bi, off);
                const float og = __shfl_xor(bg, off);
                if (ov > bv || (ov == bv && oi < bi)) { bv = ov; bi = oi; bg = og; }
            }
            if (j > 0) flg |= (vprev - bv < TAU) ? 1 : 0;
            vprev = bv;
            if (j < 8) {
                sumtop += bg;
                if (lane == j)  { myv = bg; myi = bi; }
                if (lane == bi) { work = -3e38f; mine = 1; }
            }
        }
        loadacc += (float)mine;

        if (lane < 8) {
            out_gates[(size_t)grow * 8 + lane] = myv / sumtop;
            out_idx  [(size_t)grow * 8 + lane] = (float)myi;
        }
        if (lane == 0 && flg) {
            const int pos = atomicAdd(counter, 1);
            worklist[pos] = grow;
        }
    }

    red[w][lane] = impacc;
    __syncthreads();
    if (w == 0)
        ws_imp[(size_t)blockIdx.x * NEXP + lane] =
            red[0][lane] + red[1][lane] + red[2][lane] + red[3][lane];
    __syncthreads();
    red[w][lane] = loadacc;
    __syncthreads();
    if (w == 0)
        ws_load[(size_t)blockIdx.x * NEXP + lane] =
            red[0][lane] + red[1][lane] + red[2][lane] + red[3][lane];
}

// ---------------- Kernel B2: stage-1 loss reduction (2048 -> 64) ----------------
__global__ __launch_bounds__(256) void reduce_stage(
    const float* __restrict__ ws_imp, const float* __restrict__ ws_load,
    float* __restrict__ st_imp, float* __restrict__ st_load)
{
    __shared__ float si[4][NEXP], sl[4][NEXP];
    const int tid = threadIdx.x, e = tid & 63, sub = tid >> 6;
    float a = 0.f, b = 0.f;
    #pragma unroll
    for (int i = 0; i < 8; ++i) {
        const int blk = (int)blockIdx.x * 32 + sub * 8 + i;
        a += ws_imp[(size_t)blk * NEXP + e];
        b += ws_load[(size_t)blk * NEXP + e];
    }
    si[sub][e] = a; sl[sub][e] = b;
    __syncthreads();
    if (sub == 0) {
        st_imp [(size_t)blockIdx.x * NEXP + e] = si[0][e] + si[1][e] + si[2][e] + si[3][e];
        st_load[(size_t)blockIdx.x * NEXP + e] = sl[0][e] + sl[1][e] + sl[2][e] + sl[3][e];
    }
}

// ---------------- Kernel C: fp64 repair (worklist) + loss finalize ----------------
__global__ __launch_bounds__(256) void repair_finalize(
    const float* __restrict__ x, const float* __restrict__ Wg,
    const float* __restrict__ noise, const int* __restrict__ worklist,
    const int* __restrict__ counter, const float* __restrict__ st_imp,
    const float* __restrict__ st_load, float* __restrict__ out_gates,
    float* __restrict__ out_idx, float* __restrict__ loss_out)
{
    const int tid = threadIdx.x, lane = tid & 63, w = tid >> 6;

    if (blockIdx.x == RB) {                     // ---- loss finalize ----
        __shared__ float si[4][NEXP], sl[4][NEXP];
        float a = 0.f, b = 0.f;
        #pragma unroll
        for (int j = 0; j < RBLK / 4; ++j) {
            const int blk = w * (RBLK / 4) + j;
            a += st_imp[(size_t)blk * NEXP + lane];
            b += st_load[(size_t)blk * NEXP + lane];
        }
        si[w][lane] = a; sl[w][lane] = b;
        __syncthreads();
        if (w == 0) {
            const float imp = (si[0][lane] + si[1][lane] + si[2][lane] + si[3][lane])
                              / (float)NROWS;
            const float ld  = (sl[0][lane] + sl[1][lane] + sl[2][lane] + sl[3][lane])
                              / (float)(NROWS * 8);
            float term = imp * ld;
            #pragma unroll
            for (int off = 32; off; off >>= 1) term += __shfl_xor(term, off);
            if (lane == 0) *loss_out = term * (float)NEXP;
        }
        return;
    }

    // ---- repair: ~1 flagged row per block ----
    __shared__ float xr[DDIM];          // 16 KB
    __shared__ double red64[4][NEXP];   // 2 KB
    const int count = *counter;

    for (int i = (int)blockIdx.x; i < count; i += RB) {
        const int grow = worklist[i];
        __syncthreads();                // prior iteration's LDS consumed
        #pragma unroll
        for (int q = 0; q < 4; ++q)
            ((float4*)xr)[tid + 256 * q] =
                ((const float4*)(x + (size_t)grow * DDIM))[tid + 256 * q];
        __syncthreads();

        // wave w covers k-chunk w*1024; lane = expert; 4 chains
        double a0 = 0, a1 = 0, a2 = 0, a3 = 0;
        const float* wp = Wg + (size_t)(w * 1024) * NEXP + lane;
        const float* xp = xr + w * 1024;
        for (int k = 0; k < 1024; k += 4) {
            a0 = fma((double)xp[k + 0], (double)wp[(size_t)(k + 0) * NEXP], a0);
            a1 = fma((double)xp[k + 1], (double)wp[(size_t)(k + 1) * NEXP], a1);
            a2 = fma((double)xp[k + 2], (double)wp[(size_t)(k + 2) * NEXP], a2);
            a3 = fma((double)xp[k + 3], (double)wp[(size_t)(k + 3) * NEXP], a3);
        }
        red64[w][lane] = ((a0 + a1) + a2) + a3;
        __syncthreads();

        if (w == 0) {
            const double v64 = (((red64[0][lane] + red64[1][lane]) + red64[2][lane])
                                + red64[3][lane]) + (double)noise[(size_t)grow * NEXP + lane];
            double m = v64;
            #pragma unroll
            for (int off = 32; off; off >>= 1) m = fmax(m, __shfl_xor(m, off));
            const float ex = __expf((float)(v64 - m));
            float s = ex;
            #pragma unroll
            for (int off = 32; off; off >>= 1) s += __shfl_xor(s, off);
            const float g = ex * (1.0f / s);

            double work = v64;
            float myv = 0.f, sumtop = 0.f, bg;
            int myi = 0;
            #pragma unroll
            for (int j = 0; j < 8; ++j) {
                double bv = work; int bi = lane; bg = g;
                #pragma unroll
                for (int off = 32; off; off >>= 1) {
                    const double ov = __shfl_xor(bv, off);
                    const int    oi = __shfl_xor(bi, off);
                    const float  og = __shfl_xor(bg, off);
                    if (ov > bv || (ov == bv && oi < bi)) { bv = ov; bi = oi; bg = og; }
                }
                sumtop += bg;
                if (lane == j)  { myv = bg; myi = bi; }
                if (lane == bi) work = -1e300;
            }
            if (lane < 8) {
                out_gates[(size_t)grow * 8 + lane] = myv / sumtop;
                out_idx  [(size_t)grow * 8 + lane] = (float)myi;
            }
        }
    }
}

extern "C" void kernel_launch(void* const* d_in, const int* in_sizes, int n_in,
                              void* d_out, int out_size, void* d_ws, size_t ws_size,
                              hipStream_t stream) {
    const float* x     = (const float*)d_in[0];
    const float* Wg    = (const float*)d_in[1];
    const float* noise = (const float*)d_in[2];
    float* out       = (float*)d_out;
    float* out_gates = out;
    float* out_idx   = out + (size_t)NROWS * 8;
    float* loss_out  = out + (size_t)2 * NROWS * 8;

    // ws: partials | ws_imp[CB*64] | ws_load[CB*64] | st_imp[64*64] | st_load | worklist | counter
    const size_t misc = ((size_t)2 * CB * NEXP + 2 * RBLK * NEXP + NROWS + 64) * 4;
    int ks_shift = 4;
    while (ks_shift > 0 &&
           ((size_t)64 * (1u << ks_shift) * (256 * 64) * 4 + misc) > ws_size)
        --ks_shift;
    const int KS = 1 << ks_shift;

    float* partials = (float*)d_ws;
    float* ws_imp   = partials + (size_t)64 * KS * (256 * 64);
    float* ws_load  = ws_imp + (size_t)CB * NEXP;
    float* st_imp   = ws_load + (size_t)CB * NEXP;
    float* st_load  = st_imp + (size_t)RBLK * NEXP;
    int*   worklist = (int*)(st_load + (size_t)RBLK * NEXP);
    int*   counter  = worklist + NROWS;

    gemm_partial    <<<64 * KS, 256, 0, stream>>>(x, Wg, partials, counter, ks_shift);
    combine_epilogue<<<CB,      256, 0, stream>>>(partials, noise, out_gates, out_idx,
                                                  ws_imp, ws_load, worklist, counter,
                                                  ks_shift);
    reduce_stage    <<<RBLK,    256, 0, stream>>>(ws_imp, ws_load, st_imp, st_load);
    repair_finalize <<<RB + 1,  256, 0, stream>>>(x, Wg, noise, worklist, counter,
                                                  st_imp, st_load, out_gates, out_idx,
                                                  loss_out);
}